// Round 1
// baseline (339.461 us; speedup 1.0000x reference)
//
#include <hip/hip_runtime.h>
#include <hip/hip_bf16.h>

// ---------------------------------------------------------------------------
// FFT-inspired butterfly attention, restructured:
//   P_s = scale * Wq_s @ Wk_s^T  (128x128, bf16, precomputed)
//   per pair (a, b=a+stride):  delta = x_a^T P (x_a - x_b)
//                              w0 = sigmoid(delta)
//                              v_a' = w0 va + (1-w0) vb ;  v_b' = (1-w0) va + w0 vb
// Two fused kernels: stages 0..6 (contiguous 128-blocks), stages 7..12
// (stride-128 gather, 2 lo x 64 hi per WG). v fp32 in LDS, x/P bf16 for MFMA.
// ---------------------------------------------------------------------------

typedef __bf16 bf16x8 __attribute__((ext_vector_type(8)));
typedef float  f32x4  __attribute__((ext_vector_type(4)));

#define XSTR 136   // xb/pb row stride in bf16 elems (128 + 8 pad -> 272B rows)
#define VSTR 129   // vbuf row stride in f32 (128 + 1 pad)
#define GSTR 129   // gbuf row stride in f32

#define XB_OFF   0        // 128*136*2 = 34816
#define VB_OFF   34816    // 128*129*4 = 66048
#define PB_OFF   100864   // max(128*136*2, 64*129*4) = 34816   (pb / gbuf union)
#define PART_OFF 135680   // 8*64*4 = 2048
#define WT_OFF   137728   // 64*4 = 256
#define LDS_BYTES 137984

__device__ __forceinline__ float ubits(unsigned int u) {
    union { unsigned int u; float f; } v; v.u = u; return v.f;
}
__device__ __forceinline__ unsigned short f2bf(float f) {
    union { float f; unsigned int u; } v; v.f = f;
    unsigned int u = v.u;
    return (unsigned short)((u + 0x7fffu + ((u >> 16) & 1u)) >> 16);
}

// PT[s][n][k] = P_s[k][n] = scale * sum_e Wq_s[k][e] * Wk_s[n][e]
__global__ __launch_bounds__(256)
void prep_kernel(const float* __restrict__ qkw, unsigned short* __restrict__ PT) {
    int gid = blockIdx.x * 256 + threadIdx.x;   // 13*16384 threads exactly
    int s   = gid >> 14;
    int rem = gid & 16383;
    int n   = rem >> 7;
    int k   = rem & 127;
    const float* wq = qkw + (((s << 1) + 0) * 128 + k) * 128;
    const float* wk = qkw + (((s << 1) + 1) * 128 + n) * 128;
    float acc = 0.f;
#pragma unroll 8
    for (int c = 0; c < 128; ++c) acc += wq[c] * wk[c];
    PT[gid] = f2bf(acc * 0.17677669529663687f);  // * DIM_HEAD^-0.5
}

__global__ __launch_bounds__(512)
void butterfly_kernel(const float* __restrict__ xsrc,
                      const float* __restrict__ vsrc,
                      float* __restrict__ vdst,
                      const unsigned short* __restrict__ PT,
                      int s0, int ns, int base_mul, int h_off, int rstride, int same)
{
    extern __shared__ char smem[];
    unsigned short* xb   = (unsigned short*)(smem + XB_OFF);
    float*          vbuf = (float*)(smem + VB_OFF);
    unsigned short* pb   = (unsigned short*)(smem + PB_OFF);
    float*          gbuf = (float*)(smem + PB_OFF);   // union with pb
    float*          part = (float*)(smem + PART_OFF);
    float*          wt   = (float*)(smem + WT_OFF);

    const int tid = threadIdx.x;
    const int b   = blockIdx.x >> 6;
    const int sub = blockIdx.x & 63;
    const int base = b * 8192 + sub * base_mul;

    // ---- load: xsrc -> xb (bf16) [+ vbuf if same], else vsrc -> vbuf ----
    {
        const int rl = tid >> 5;      // 0..15
        const int c4 = tid & 31;      // float4 column
        for (int j = 0; j < 8; ++j) {
            int i = j * 16 + rl;      // local row 0..127
            int gp = base + (i >> 6) * h_off + (i & 63) * rstride;
            float4 val = ((const float4*)xsrc)[gp * 32 + c4];
            int xo = i * XSTR + c4 * 4;
            ushort4 us;
            us.x = f2bf(val.x); us.y = f2bf(val.y);
            us.z = f2bf(val.z); us.w = f2bf(val.w);
            *(ushort4*)(xb + xo) = us;
            if (same) {
                int vo = i * VSTR + c4 * 4;
                vbuf[vo+0] = val.x; vbuf[vo+1] = val.y;
                vbuf[vo+2] = val.z; vbuf[vo+3] = val.w;
            }
        }
        if (!same) {
            for (int j = 0; j < 8; ++j) {
                int i = j * 16 + rl;
                int gp = base + (i >> 6) * h_off + (i & 63) * rstride;
                float4 val = ((const float4*)vsrc)[gp * 32 + c4];
                int vo = i * VSTR + c4 * 4;
                vbuf[vo+0] = val.x; vbuf[vo+1] = val.y;
                vbuf[vo+2] = val.z; vbuf[vo+3] = val.w;
            }
        }
    }

    const int lane   = tid & 63;
    const int wv     = tid >> 6;     // 0..7
    const int lane15 = lane & 15;
    const int quad   = lane >> 4;    // 0..3
    const int pw     = wv >> 1;      // pair block 0..3 (16 pairs each)
    const int ch     = wv & 1;       // column half (64 cols each)
    const int pr_d   = tid & 63;     // pair id for dot/mix phases
    const int q8     = tid >> 6;     // 16-elem slice id

    for (int u = 0; u < ns; ++u) {
        const int t = 1 << u;
        const int s = s0 + u;

        __syncthreads();  // S1: prior gbuf readers / vbuf writers done
        // ---- stage P load: PT[s] -> pb ----
        {
            const uint4* src = (const uint4*)(PT + s * 16384);
#pragma unroll
            for (int j = 0; j < 4; ++j) {
                int c  = j * 512 + tid;   // 8-elem chunk id, 0..2047
                int n  = c >> 4;
                int c8 = c & 15;
                uint4 v = src[c];
                *(uint4*)((char*)pb + n * (XSTR * 2) + c8 * 16) = v;
            }
        }
        __syncthreads();  // S2: pb ready

        // ---- GEMM: G[64x128] = Xa(bf16) @ P(bf16), fp32 acc ----
        {
            const int m    = 16 * pw + lane15;
            const int ar_g = ((m & ~(t - 1)) << 1) | (m & (t - 1));
            f32x4 acc0 = {0.f,0.f,0.f,0.f}, acc1 = {0.f,0.f,0.f,0.f};
            f32x4 acc2 = {0.f,0.f,0.f,0.f}, acc3 = {0.f,0.f,0.f,0.f};
            const unsigned short* abase = xb + ar_g * XSTR + quad * 8;
            const unsigned short* bbase = pb + (ch * 64 + lane15) * XSTR + quad * 8;
#pragma unroll
            for (int k = 0; k < 4; ++k) {
                bf16x8 av = *(const bf16x8*)(abase + 32 * k);
                bf16x8 b0 = *(const bf16x8*)(bbase + 32 * k);
                bf16x8 b1 = *(const bf16x8*)(bbase + 16 * XSTR + 32 * k);
                bf16x8 b2 = *(const bf16x8*)(bbase + 32 * XSTR + 32 * k);
                bf16x8 b3 = *(const bf16x8*)(bbase + 48 * XSTR + 32 * k);
                acc0 = __builtin_amdgcn_mfma_f32_16x16x32_bf16(av, b0, acc0, 0, 0, 0);
                acc1 = __builtin_amdgcn_mfma_f32_16x16x32_bf16(av, b1, acc1, 0, 0, 0);
                acc2 = __builtin_amdgcn_mfma_f32_16x16x32_bf16(av, b2, acc2, 0, 0, 0);
                acc3 = __builtin_amdgcn_mfma_f32_16x16x32_bf16(av, b3, acc3, 0, 0, 0);
            }
            __syncthreads();  // S3: pb reads done; overwrite with gbuf
            // C/D layout: col = lane&15, row = quad*4 + reg
#pragma unroll
            for (int r = 0; r < 4; ++r) {
                int prow = 16 * pw + quad * 4 + r;
                int colb = ch * 64 + lane15;
                gbuf[prow * GSTR + colb +  0] = acc0[r];
                gbuf[prow * GSTR + colb + 16] = acc1[r];
                gbuf[prow * GSTR + colb + 32] = acc2[r];
                gbuf[prow * GSTR + colb + 48] = acc3[r];
            }
        }
        __syncthreads();  // S4: gbuf ready

        // ---- dot: delta_pr = sum_n G[pr][n] * (x[ar][n] - x[br][n]) ----
        {
            int ar = ((pr_d & ~(t - 1)) << 1) | (pr_d & (t - 1));
            int br = ar + t;
            float sum = 0.f;
            const float* g = gbuf + pr_d * GSTR + q8 * 16;
            const unsigned int* xa  = (const unsigned int*)(xb + ar * XSTR + q8 * 16);
            const unsigned int* xbp = (const unsigned int*)(xb + br * XSTR + q8 * 16);
#pragma unroll
            for (int jj = 0; jj < 8; ++jj) {
                unsigned int ua = xa[jj], ub = xbp[jj];
                float a0 = ubits(ua << 16), a1 = ubits(ua & 0xffff0000u);
                float b0 = ubits(ub << 16), b1 = ubits(ub & 0xffff0000u);
                sum += g[2*jj]   * (a0 - b0);
                sum += g[2*jj+1] * (a1 - b1);
            }
            part[q8 * 64 + pr_d] = sum;
        }
        __syncthreads();  // S5: partials ready
        if (tid < 64) {
            float d = 0.f;
#pragma unroll
            for (int w = 0; w < 8; ++w) d += part[w * 64 + tid];
            wt[tid] = 1.0f / (1.0f + expf(-d));   // softmax([s_aa,s_ab])[0]
        }
        __syncthreads();  // S6: weights ready

        // ---- mix ----
        {
            int ar = ((pr_d & ~(t - 1)) << 1) | (pr_d & (t - 1));
            int br = ar + t;
            float w0 = wt[pr_d];
            float w1 = 1.0f - w0;
            float* va  = vbuf + ar * VSTR + q8 * 16;
            float* vb_ = vbuf + br * VSTR + q8 * 16;
#pragma unroll
            for (int jj = 0; jj < 16; ++jj) {
                float a = va[jj], c = vb_[jj];
                va[jj]  = w0 * a + w1 * c;
                vb_[jj] = w1 * a + w0 * c;
            }
        }
    }

    __syncthreads();
    // ---- store vbuf -> vdst ----
    {
        const int rl = tid >> 5;
        const int c4 = tid & 31;
        for (int j = 0; j < 8; ++j) {
            int i = j * 16 + rl;
            int gp = base + (i >> 6) * h_off + (i & 63) * rstride;
            int vo = i * VSTR + c4 * 4;
            float4 val;
            val.x = vbuf[vo+0]; val.y = vbuf[vo+1];
            val.z = vbuf[vo+2]; val.w = vbuf[vo+3];
            ((float4*)vdst)[gp * 32 + c4] = val;
        }
    }
}

extern "C" void kernel_launch(void* const* d_in, const int* in_sizes, int n_in,
                              void* d_out, int out_size, void* d_ws, size_t ws_size,
                              hipStream_t stream) {
    const float* x   = (const float*)d_in[0];
    const float* qkw = (const float*)d_in[1];
    float* out = (float*)d_out;
    unsigned short* PT = (unsigned short*)d_ws;   // 13*16384 bf16 = 416 KB

    // opt-in to >64KB dynamic LDS (gfx950 group segment is 160 KiB)
    (void)hipFuncSetAttribute((const void*)butterfly_kernel,
                              hipFuncAttributeMaxDynamicSharedMemorySize, LDS_BYTES);

    // P_s = scale * Wq_s Wk_s^T (stored transposed, bf16): 13*16384 elems
    prep_kernel<<<832, 256, 0, stream>>>(qkw, PT);

    // stages 0..6: contiguous 128-position blocks; v init = x; out -> d_out
    butterfly_kernel<<<1024, 512, LDS_BYTES, stream>>>(
        x, x, out, PT, /*s0=*/0, /*ns=*/7, /*base_mul=*/128, /*h_off=*/64, /*rstride=*/1, /*same=*/1);

    // stages 7..12: rows lo0+{0,1} x 64 his (stride 128); in-place on d_out
    butterfly_kernel<<<1024, 512, LDS_BYTES, stream>>>(
        x, out, out, PT, /*s0=*/7, /*ns=*/6, /*base_mul=*/2, /*h_off=*/1, /*rstride=*/128, /*same=*/0);
}

// Round 2
// 296.210 us; speedup vs baseline: 1.1460x; 1.1460x over previous
//
#include <hip/hip_runtime.h>
#include <hip/hip_bf16.h>

// ---------------------------------------------------------------------------
// FFT butterfly attention. delta = x_a^T P (x_a - x_b), P = scale*Wq*Wk^T
// (bf16, precomputed by MFMA prep). w0 = sigmoid(delta); v' = mix(va, vb).
// v is held in REGISTERS (rows: bits0-5 = lane, bit6 = vlo/vhi; cols: 16/wave)
// and mixed via DPP quad_perm (u=0,1), ds_bpermute (u=2..5), in-thread (u=6).
// Weights: G = Xa @ P via MFMA (A from LDS xb, B direct from global PT),
// delta via column-parallel row-dot + 6-step DPP wave reduction.
// LDS: xb 34.8K + gbuf 33.8K + wt = 68.9K -> 2 WGs/CU. 2 barriers/stage.
// ---------------------------------------------------------------------------

typedef __bf16 bf16x8 __attribute__((ext_vector_type(8)));
typedef float  f32x4  __attribute__((ext_vector_type(4)));

#define XSTR 136                    // bf16 elems per xb row (128 + 8 pad)
#define GSTR 132                    // f32 elems per gbuf row (even, 2-way-free writes)
#define XB_BYTES  (128 * XSTR * 2)  // 34816
#define GB_OFF    XB_BYTES
#define GB_BYTES  (64 * GSTR * 4)   // 33792
#define WT_OFF    (GB_OFF + GB_BYTES)
#define LDS_MAIN  (WT_OFF + 64 * 4) // 68864 -> 2 WGs/CU (137728 <= 163840)
#define PREP_LDS  (2 * XB_BYTES)    // 69632

__device__ __forceinline__ float ubits(unsigned int u) {
    union { unsigned int u; float f; } v; v.u = u; return v.f;
}
__device__ __forceinline__ unsigned short f2bf(float f) {
    union { float f; unsigned int u; } v; v.f = f;
    unsigned int u = v.u;
    return (unsigned short)((u + 0x7fffu + ((u >> 16) & 1u)) >> 16);
}

// dpp move: partner/shift value, invalid lanes -> 0 (old=0 either way)
#define DPP_MOV_F(x, ctrl) \
    __int_as_float(__builtin_amdgcn_update_dpp(0, __float_as_int(x), (ctrl), 0xF, 0xF, true))
#define DPP_ADD_F(s, ctrl) s += DPP_MOV_F(s, ctrl)

// ---------------- prep: PT[s][n][k] = scale * sum_e Wq[k][e] Wk[n][e] -------
__global__ __launch_bounds__(512)
void prep_kernel(const float* __restrict__ qkw, unsigned short* __restrict__ PT) {
    extern __shared__ char smem[];
    unsigned short* wkb = (unsigned short*)smem;              // A: Wk rows (n)
    unsigned short* wqb = (unsigned short*)(smem + XB_BYTES); // B: Wq rows (k)
    const int s = blockIdx.x;
    const float* Wq = qkw + (size_t)s * 32768;
    const float* Wk = Wq + 16384;
    const int tid = threadIdx.x;
    const int rl = tid >> 5, c4 = tid & 31;
#pragma unroll
    for (int j = 0; j < 8; ++j) {
        int r = j * 16 + rl;
        float4 vq = ((const float4*)Wq)[r * 32 + c4];
        float4 vk = ((const float4*)Wk)[r * 32 + c4];
        ushort4 uq; uq.x = f2bf(vq.x); uq.y = f2bf(vq.y); uq.z = f2bf(vq.z); uq.w = f2bf(vq.w);
        ushort4 uk; uk.x = f2bf(vk.x); uk.y = f2bf(vk.y); uk.z = f2bf(vk.z); uk.w = f2bf(vk.w);
        *(ushort4*)(wqb + r * XSTR + c4 * 4) = uq;
        *(ushort4*)(wkb + r * XSTR + c4 * 4) = uk;
    }
    __syncthreads();
    const int lane = tid & 63, w = tid >> 6;
    const int lane15 = lane & 15, quad = lane >> 4;
    f32x4 acc[8] = {};
#pragma unroll
    for (int kk = 0; kk < 4; ++kk) {
        bf16x8 a = *(const bf16x8*)(wkb + (w * 16 + lane15) * XSTR + kk * 32 + quad * 8);
#pragma unroll
        for (int ct = 0; ct < 8; ++ct) {
            bf16x8 b = *(const bf16x8*)(wqb + (ct * 16 + lane15) * XSTR + kk * 32 + quad * 8);
            acc[ct] = __builtin_amdgcn_mfma_f32_16x16x32_bf16(a, b, acc[ct], 0, 0, 0);
        }
    }
    unsigned short* dst = PT + s * 16384;
#pragma unroll
    for (int ct = 0; ct < 8; ++ct)
#pragma unroll
        for (int r = 0; r < 4; ++r) {
            int n = w * 16 + quad * 4 + r;
            int k = ct * 16 + lane15;
            dst[n * 128 + k] = f2bf(acc[ct][r] * 0.17677669529663687f);
        }
}

// ---------------- fused butterfly stages ------------------------------------
__global__ __launch_bounds__(512, 4)
void butterfly_kernel(const float* __restrict__ xsrc,
                      const float* __restrict__ vsrc,
                      float* __restrict__ vdst,
                      const unsigned short* __restrict__ PT,
                      int s0, int ns, int base_mul, int h_off, int rstride)
{
    extern __shared__ char smem[];
    unsigned short* xb   = (unsigned short*)smem;
    float*          gbuf = (float*)(smem + GB_OFF);
    float*          wt   = (float*)(smem + WT_OFF);

    const int tid  = threadIdx.x;
    const int b    = blockIdx.x >> 6;
    const int sub  = blockIdx.x & 63;
    const int base = b * 8192 + sub * base_mul;

    // ---- stage x -> xb (bf16), coalesced ----
    {
        const int rl = tid >> 5, c4 = tid & 31;
#pragma unroll
        for (int j = 0; j < 8; ++j) {
            int i  = j * 16 + rl;
            int gp = base + (i >> 6) * h_off + (i & 63) * rstride;
            float4 val = ((const float4*)xsrc)[gp * 32 + c4];
            ushort4 us; us.x = f2bf(val.x); us.y = f2bf(val.y);
            us.z = f2bf(val.z); us.w = f2bf(val.w);
            *(ushort4*)(xb + i * XSTR + c4 * 4) = us;
        }
    }

    const int lane = tid & 63, w = tid >> 6;
    const int lane15 = lane & 15, quad = lane >> 4;
    const int rg = w >> 2, cg = w & 3;

    // ---- v into registers: rows lane / lane+64, cols w*16..w*16+15 ----
    float vlo[16], vhi[16];
    {
        const float* p0 = vsrc + (size_t)(base + lane * rstride) * 128 + w * 16;
        const float* p1 = vsrc + (size_t)(base + h_off + lane * rstride) * 128 + w * 16;
#pragma unroll
        for (int j = 0; j < 4; ++j) {
            float4 a = ((const float4*)p0)[j];
            float4 c = ((const float4*)p1)[j];
            vlo[4*j] = a.x; vlo[4*j+1] = a.y; vlo[4*j+2] = a.z; vlo[4*j+3] = a.w;
            vhi[4*j] = c.x; vhi[4*j+1] = c.y; vhi[4*j+2] = c.z; vhi[4*j+3] = c.w;
        }
    }
    __syncthreads();   // xb ready

    for (int u = 0; u < ns; ++u) {
        const int t   = 1 << u;
        const int tm1 = t - 1;

        // ---- GEMM: G[64x128] = Xa @ P; B-frags direct from global PT ----
        {
            const unsigned short* PTs = PT + (s0 + u) * 16384;
            uint4 bfr[8];
#pragma unroll
            for (int ct = 0; ct < 2; ++ct)
#pragma unroll
                for (int kk = 0; kk < 4; ++kk)
                    bfr[ct * 4 + kk] = *(const uint4*)(PTs + (cg * 32 + ct * 16 + lane15) * 128 + kk * 32 + quad * 8);

            const int m0 = rg * 32 + lane15, m1 = m0 + 16;
            const int ar0 = ((m0 & ~tm1) << 1) | (m0 & tm1);
            const int ar1 = ((m1 & ~tm1) << 1) | (m1 & tm1);
            f32x4 acc[2][2] = {};
#pragma unroll
            for (int kk = 0; kk < 4; ++kk) {
                bf16x8 a0 = *(const bf16x8*)(xb + ar0 * XSTR + kk * 32 + quad * 8);
                bf16x8 a1 = *(const bf16x8*)(xb + ar1 * XSTR + kk * 32 + quad * 8);
#pragma unroll
                for (int ct = 0; ct < 2; ++ct) {
                    union { uint4 u; bf16x8 b; } cv; cv.u = bfr[ct * 4 + kk];
                    acc[0][ct] = __builtin_amdgcn_mfma_f32_16x16x32_bf16(a0, cv.b, acc[0][ct], 0, 0, 0);
                    acc[1][ct] = __builtin_amdgcn_mfma_f32_16x16x32_bf16(a1, cv.b, acc[1][ct], 0, 0, 0);
                }
            }
#pragma unroll
            for (int rt = 0; rt < 2; ++rt)
#pragma unroll
                for (int ct = 0; ct < 2; ++ct)
#pragma unroll
                    for (int r = 0; r < 4; ++r)
                        gbuf[(rg * 32 + rt * 16 + quad * 4 + r) * GSTR + cg * 32 + ct * 16 + lane15]
                            = acc[rt][ct][r];
        }
        __syncthreads();   // S4: gbuf ready (also fences wt of prev stage)

        // ---- dot: per pair, column-parallel + DPP wave reduce ----
#pragma unroll
        for (int j = 0; j < 8; ++j) {
            int p  = w * 8 + j;
            int ar = ((p & ~tm1) << 1) | (p & tm1);
            int br = ar + t;
            unsigned int ua = ((const unsigned int*)(xb + ar * XSTR))[lane];
            unsigned int ub = ((const unsigned int*)(xb + br * XSTR))[lane];
            float2 g = *(const float2*)(gbuf + p * GSTR + lane * 2);
            float a0 = ubits(ua << 16), a1 = ubits(ua & 0xffff0000u);
            float b0 = ubits(ub << 16), b1 = ubits(ub & 0xffff0000u);
            float sm = g.x * (a0 - b0) + g.y * (a1 - b1);
            DPP_ADD_F(sm, 0x111);  // row_shr:1
            DPP_ADD_F(sm, 0x112);  // row_shr:2
            DPP_ADD_F(sm, 0x114);  // row_shr:4
            DPP_ADD_F(sm, 0x118);  // row_shr:8
            DPP_ADD_F(sm, 0x142);  // row_bcast:15
            DPP_ADD_F(sm, 0x143);  // row_bcast:31
            if (lane == 63) wt[p] = 1.0f / (1.0f + __expf(-sm));
        }
        __syncthreads();   // S5: weights ready

        // ---- mix (registers + cross-lane) ----
        if (u < 6) {
            const int plo = ((lane >> (u + 1)) << u) | (lane & tm1);
            const float w0l = wt[plo],      w1l = 1.0f - w0l;
            const float w0h = wt[plo + 32], w1h = 1.0f - w0h;
            if (u == 0) {
#pragma unroll
                for (int j = 0; j < 16; ++j) {
                    float pl = DPP_MOV_F(vlo[j], 0xB1);  // quad_perm xor1
                    float ph = DPP_MOV_F(vhi[j], 0xB1);
                    vlo[j] = w0l * vlo[j] + w1l * pl;
                    vhi[j] = w0h * vhi[j] + w1h * ph;
                }
            } else if (u == 1) {
#pragma unroll
                for (int j = 0; j < 16; ++j) {
                    float pl = DPP_MOV_F(vlo[j], 0x4E);  // quad_perm xor2
                    float ph = DPP_MOV_F(vhi[j], 0x4E);
                    vlo[j] = w0l * vlo[j] + w1l * pl;
                    vhi[j] = w0h * vhi[j] + w1h * ph;
                }
            } else {
                const int baddr = (lane ^ t) << 2;
#pragma unroll
                for (int j = 0; j < 16; ++j) {
                    float pl = __int_as_float(__builtin_amdgcn_ds_bpermute(baddr, __float_as_int(vlo[j])));
                    float ph = __int_as_float(__builtin_amdgcn_ds_bpermute(baddr, __float_as_int(vhi[j])));
                    vlo[j] = w0l * vlo[j] + w1l * pl;
                    vhi[j] = w0h * vhi[j] + w1h * ph;
                }
            }
        } else {            // u == 6 (kernel 1 only): partner is in-thread
            const float w0 = wt[lane], w1 = 1.0f - w0;
#pragma unroll
            for (int j = 0; j < 16; ++j) {
                float a = vlo[j], c = vhi[j];
                vlo[j] = w0 * a + w1 * c;
                vhi[j] = w1 * a + w0 * c;
            }
        }
    }

    // ---- store v registers -> vdst ----
    {
        float* p0 = vdst + (size_t)(base + lane * rstride) * 128 + w * 16;
        float* p1 = vdst + (size_t)(base + h_off + lane * rstride) * 128 + w * 16;
#pragma unroll
        for (int j = 0; j < 4; ++j) {
            float4 a; a.x = vlo[4*j]; a.y = vlo[4*j+1]; a.z = vlo[4*j+2]; a.w = vlo[4*j+3];
            float4 c; c.x = vhi[4*j]; c.y = vhi[4*j+1]; c.z = vhi[4*j+2]; c.w = vhi[4*j+3];
            ((float4*)p0)[j] = a;
            ((float4*)p1)[j] = c;
        }
    }
}

extern "C" void kernel_launch(void* const* d_in, const int* in_sizes, int n_in,
                              void* d_out, int out_size, void* d_ws, size_t ws_size,
                              hipStream_t stream) {
    const float* x   = (const float*)d_in[0];
    const float* qkw = (const float*)d_in[1];
    float* out = (float*)d_out;
    unsigned short* PT = (unsigned short*)d_ws;   // 13*16384 bf16 = 416 KB

    (void)hipFuncSetAttribute((const void*)prep_kernel,
                              hipFuncAttributeMaxDynamicSharedMemorySize, PREP_LDS);
    (void)hipFuncSetAttribute((const void*)butterfly_kernel,
                              hipFuncAttributeMaxDynamicSharedMemorySize, LDS_MAIN);

    prep_kernel<<<13, 512, PREP_LDS, stream>>>(qkw, PT);

    // stages 0..6: contiguous 128-position blocks; v init = x
    butterfly_kernel<<<1024, 512, LDS_MAIN, stream>>>(
        x, x, out, PT, /*s0=*/0, /*ns=*/7, /*base_mul=*/128, /*h_off=*/64, /*rstride=*/1);

    // stages 7..12: 2 lo x 64 hi (stride 128); in-place on d_out
    butterfly_kernel<<<1024, 512, LDS_MAIN, stream>>>(
        x, out, out, PT, /*s0=*/7, /*ns=*/6, /*base_mul=*/2, /*h_off=*/1, /*rstride=*/128);
}

// Round 3
// 268.120 us; speedup vs baseline: 1.2661x; 1.1048x over previous
//
#include <hip/hip_runtime.h>
#include <hip/hip_bf16.h>

// ---------------------------------------------------------------------------
// FFT butterfly attention. delta = x_a^T P (x_a - x_b), P = scale*Wq*Wk^T
// (bf16, MFMA prep). w0 = sigmoid(delta); v' = mix(va, vb).
//
// v register layout (pair-local): at stage u, lane L holds BOTH partners:
//   vlo = row ((L>>u)<<(u+1)) | (L & (2^u-1)),  vhi = vlo + 2^u
// -> mix is pure in-thread VALU; weight index is wt[lane] at every stage.
// Between stages, each lane exchanges exactly one value with lane L^2^u
// (DPP quad_perm / ds_swizzle xor / ds_bpermute), fused into the mix.
// Weights: G = Xa @ P via MFMA (A from LDS xb, B direct from global PT),
// delta via split-wave dot (2 pairs/iter, b64+b128 reads) + 5-step DPP reduce.
// LDS: xb 34.8K + gbuf 33.8K + wt = 68.9K -> 2 WGs/CU. 2 barriers/stage.
// ---------------------------------------------------------------------------

typedef __bf16 bf16x8 __attribute__((ext_vector_type(8)));
typedef float  f32x4  __attribute__((ext_vector_type(4)));

#define XSTR 136                    // bf16 elems per xb row (128 + 8 pad)
#define GSTR 132                    // f32 elems per gbuf row
#define XB_BYTES  (128 * XSTR * 2)  // 34816
#define GB_OFF    XB_BYTES
#define GB_BYTES  (64 * GSTR * 4)   // 33792
#define WT_OFF    (GB_OFF + GB_BYTES)
#define LDS_MAIN  (WT_OFF + 64 * 4) // 68864 -> 2 WGs/CU
#define PREP_LDS  (2 * XB_BYTES)    // 69632

__device__ __forceinline__ float ubits(unsigned int u) {
    union { unsigned int u; float f; } v; v.u = u; return v.f;
}
__device__ __forceinline__ unsigned short f2bf(float f) {
    union { float f; unsigned int u; } v; v.f = f;
    unsigned int u = v.u;
    return (unsigned short)((u + 0x7fffu + ((u >> 16) & 1u)) >> 16);
}

#define DPP_MOV_F(x, ctrl) \
    __int_as_float(__builtin_amdgcn_update_dpp(0, __float_as_int(x), (ctrl), 0xF, 0xF, true))
#define DPP_ADD_F(s, ctrl) s += DPP_MOV_F(s, ctrl)

// cross-lane xor exchange with lane ^ (1<<u); u is compile-time-folded
__device__ __forceinline__ float xlane_u(float x, int u, int lane) {
    if (u == 0) return DPP_MOV_F(x, 0xB1);   // quad_perm xor1
    if (u == 1) return DPP_MOV_F(x, 0x4E);   // quad_perm xor2
    if (u == 2) return __int_as_float(__builtin_amdgcn_ds_swizzle(__float_as_int(x), 0x101F)); // xor4
    if (u == 3) return __int_as_float(__builtin_amdgcn_ds_swizzle(__float_as_int(x), 0x201F)); // xor8
    if (u == 4) return __int_as_float(__builtin_amdgcn_ds_swizzle(__float_as_int(x), 0x401F)); // xor16
    return __int_as_float(__builtin_amdgcn_ds_bpermute((lane ^ 32) << 2, __float_as_int(x))); // xor32
}

// ---------------- prep: PT[s][n][k] = scale * sum_e Wq[k][e] Wk[n][e] -------
__global__ __launch_bounds__(512)
void prep_kernel(const float* __restrict__ qkw, unsigned short* __restrict__ PT) {
    extern __shared__ char smem[];
    unsigned short* wkb = (unsigned short*)smem;              // A: Wk rows (n)
    unsigned short* wqb = (unsigned short*)(smem + XB_BYTES); // B: Wq rows (k)
    const int s = blockIdx.x;
    const float* Wq = qkw + (size_t)s * 32768;
    const float* Wk = Wq + 16384;
    const int tid = threadIdx.x;
    const int rl = tid >> 5, c4 = tid & 31;
#pragma unroll
    for (int j = 0; j < 8; ++j) {
        int r = j * 16 + rl;
        float4 vq = ((const float4*)Wq)[r * 32 + c4];
        float4 vk = ((const float4*)Wk)[r * 32 + c4];
        ushort4 uq; uq.x = f2bf(vq.x); uq.y = f2bf(vq.y); uq.z = f2bf(vq.z); uq.w = f2bf(vq.w);
        ushort4 uk; uk.x = f2bf(vk.x); uk.y = f2bf(vk.y); uk.z = f2bf(vk.z); uk.w = f2bf(vk.w);
        *(ushort4*)(wqb + r * XSTR + c4 * 4) = uq;
        *(ushort4*)(wkb + r * XSTR + c4 * 4) = uk;
    }
    __syncthreads();
    const int lane = tid & 63, w = tid >> 6;
    const int lane15 = lane & 15, quad = lane >> 4;
    f32x4 acc[8] = {};
#pragma unroll
    for (int kk = 0; kk < 4; ++kk) {
        bf16x8 a = *(const bf16x8*)(wkb + (w * 16 + lane15) * XSTR + kk * 32 + quad * 8);
#pragma unroll
        for (int ct = 0; ct < 8; ++ct) {
            bf16x8 b = *(const bf16x8*)(wqb + (ct * 16 + lane15) * XSTR + kk * 32 + quad * 8);
            acc[ct] = __builtin_amdgcn_mfma_f32_16x16x32_bf16(a, b, acc[ct], 0, 0, 0);
        }
    }
    unsigned short* dst = PT + s * 16384;
#pragma unroll
    for (int ct = 0; ct < 8; ++ct)
#pragma unroll
        for (int r = 0; r < 4; ++r) {
            int n = w * 16 + quad * 4 + r;
            int k = ct * 16 + lane15;
            dst[n * 128 + k] = f2bf(acc[ct][r] * 0.17677669529663687f);
        }
}

// ---------------- fused butterfly stages ------------------------------------
template<int NS>
__global__ __launch_bounds__(512, 4)
void butterfly_kernel(const float* __restrict__ xsrc,
                      const float* __restrict__ vsrc,
                      float* __restrict__ vdst,
                      const unsigned short* __restrict__ PT,
                      int s0, int base_mul, int h_off, int rstride)
{
    extern __shared__ char smem[];
    unsigned short* xb   = (unsigned short*)smem;
    float*          gbuf = (float*)(smem + GB_OFF);
    float*          wt   = (float*)(smem + WT_OFF);

    const int tid  = threadIdx.x;
    const int b    = blockIdx.x >> 6;
    const int sub  = blockIdx.x & 63;
    const int base = b * 8192 + sub * base_mul;

    // ---- stage x -> xb (bf16), coalesced ----
    {
        const int rl = tid >> 5, c4 = tid & 31;
#pragma unroll
        for (int j = 0; j < 8; ++j) {
            int i  = j * 16 + rl;
            int gp = base + (i >> 6) * h_off + (i & 63) * rstride;
            float4 val = ((const float4*)xsrc)[gp * 32 + c4];
            ushort4 us; us.x = f2bf(val.x); us.y = f2bf(val.y);
            us.z = f2bf(val.z); us.w = f2bf(val.w);
            *(ushort4*)(xb + i * XSTR + c4 * 4) = us;
        }
    }

    const int lane = tid & 63, w = tid >> 6;
    const int lane15 = lane & 15, quad = lane >> 4;
    const int rg = w >> 2, cg = w & 3;

    // ---- v into registers, pair-local for stage 0: rows (2L, 2L+1) ----
    float vlo[16], vhi[16];
    {
        int r0 = 2 * lane, r1 = r0 + 1;
        int gp0 = base + (r0 >> 6) * h_off + (r0 & 63) * rstride;
        int gp1 = base + (r1 >> 6) * h_off + (r1 & 63) * rstride;
        const float* p0 = vsrc + (size_t)gp0 * 128 + w * 16;
        const float* p1 = vsrc + (size_t)gp1 * 128 + w * 16;
#pragma unroll
        for (int j = 0; j < 4; ++j) {
            float4 a = ((const float4*)p0)[j];
            float4 c = ((const float4*)p1)[j];
            vlo[4*j] = a.x; vlo[4*j+1] = a.y; vlo[4*j+2] = a.z; vlo[4*j+3] = a.w;
            vhi[4*j] = c.x; vhi[4*j+1] = c.y; vhi[4*j+2] = c.z; vhi[4*j+3] = c.w;
        }
    }
    __syncthreads();   // xb ready

#pragma unroll
    for (int u = 0; u < NS; ++u) {
        const int t   = 1 << u;
        const int tm1 = t - 1;

        // ---- GEMM: G[64x128] = Xa @ P; B-frags direct from global PT ----
        {
            const unsigned short* PTs = PT + (s0 + u) * 16384;
            uint4 bfr[8];
#pragma unroll
            for (int ct = 0; ct < 2; ++ct)
#pragma unroll
                for (int kk = 0; kk < 4; ++kk)
                    bfr[ct * 4 + kk] = *(const uint4*)(PTs + (cg * 32 + ct * 16 + lane15) * 128 + kk * 32 + quad * 8);

            const int m0 = rg * 32 + lane15, m1 = m0 + 16;
            const int ar0 = ((m0 & ~tm1) << 1) | (m0 & tm1);
            const int ar1 = ((m1 & ~tm1) << 1) | (m1 & tm1);
            f32x4 acc[2][2] = {};
#pragma unroll
            for (int kk = 0; kk < 4; ++kk) {
                bf16x8 a0 = *(const bf16x8*)(xb + ar0 * XSTR + kk * 32 + quad * 8);
                bf16x8 a1 = *(const bf16x8*)(xb + ar1 * XSTR + kk * 32 + quad * 8);
#pragma unroll
                for (int ct = 0; ct < 2; ++ct) {
                    union { uint4 u; bf16x8 b; } cv; cv.u = bfr[ct * 4 + kk];
                    acc[0][ct] = __builtin_amdgcn_mfma_f32_16x16x32_bf16(a0, cv.b, acc[0][ct], 0, 0, 0);
                    acc[1][ct] = __builtin_amdgcn_mfma_f32_16x16x32_bf16(a1, cv.b, acc[1][ct], 0, 0, 0);
                }
            }
#pragma unroll
            for (int rt = 0; rt < 2; ++rt)
#pragma unroll
                for (int ct = 0; ct < 2; ++ct)
#pragma unroll
                    for (int r = 0; r < 4; ++r)
                        gbuf[(rg * 32 + rt * 16 + quad * 4 + r) * GSTR + cg * 32 + ct * 16 + lane15]
                            = acc[rt][ct][r];
        }
        __syncthreads();   // S4: gbuf ready (also fences wt reads of prev stage)

        // ---- dot: 2 pairs per iter (32 lanes x 4 cols each) + DPP reduce ----
        {
            const int half = lane >> 5, l32 = lane & 31, c0 = l32 * 4;
#pragma unroll
            for (int it = 0; it < 4; ++it) {
                int p  = w * 8 + it * 2 + half;
                int ar = ((p & ~tm1) << 1) | (p & tm1);
                int br = ar + t;
                uint2 ua = *(const uint2*)(xb + ar * XSTR + c0);
                uint2 ub = *(const uint2*)(xb + br * XSTR + c0);
                float4 g = *(const float4*)(gbuf + p * GSTR + c0);
                float a0 = ubits(ua.x << 16), a1 = ubits(ua.x & 0xffff0000u);
                float a2 = ubits(ua.y << 16), a3 = ubits(ua.y & 0xffff0000u);
                float b0 = ubits(ub.x << 16), b1 = ubits(ub.x & 0xffff0000u);
                float b2 = ubits(ub.y << 16), b3 = ubits(ub.y & 0xffff0000u);
                float sm = g.x * (a0 - b0) + g.y * (a1 - b1)
                         + g.z * (a2 - b2) + g.w * (a3 - b3);
                DPP_ADD_F(sm, 0x111);  // row_shr:1
                DPP_ADD_F(sm, 0x112);  // row_shr:2
                DPP_ADD_F(sm, 0x114);  // row_shr:4
                DPP_ADD_F(sm, 0x118);  // row_shr:8
                DPP_ADD_F(sm, 0x142);  // row_bcast:15 -> lane31 / lane63 hold sums
                if (l32 == 31) wt[p] = 1.0f / (1.0f + __expf(-sm));
            }
        }
        __syncthreads();   // S5: weights ready

        // ---- mix (in-thread) + fused pair exchange for next stage ----
        {
            const float w0 = wt[lane];
            if (u < NS - 1) {
                const bool isE = ((lane >> u) & 1) == 0;
                const float wk = isE ? w0 : 1.0f - w0;
#pragma unroll
                for (int j = 0; j < 16; ++j) {
                    float a = vlo[j], c = vhi[j];
                    float s    = a + c;
                    float keep = c + wk * (a - c);   // E: out_a ; O: out_b
                    float send = s - keep;           // E: out_b ; O: out_a
                    float ex   = xlane_u(send, u, lane);
                    vlo[j] = isE ? keep : ex;
                    vhi[j] = isE ? ex : keep;
                }
            } else {
                const float w1 = 1.0f - w0;
#pragma unroll
                for (int j = 0; j < 16; ++j) {
                    float a = vlo[j], c = vhi[j];
                    float oa = w0 * a + w1 * c;
                    vlo[j] = oa;
                    vhi[j] = a + c - oa;
                }
            }
        }
    }

    // ---- store v registers -> vdst (layout of final stage NS-1) ----
    {
        const int FU = NS - 1;
        int r0 = ((lane >> FU) << (FU + 1)) | (lane & ((1 << FU) - 1));
        int r1 = r0 + (1 << FU);
        int gp0 = base + (r0 >> 6) * h_off + (r0 & 63) * rstride;
        int gp1 = base + (r1 >> 6) * h_off + (r1 & 63) * rstride;
        float* p0 = vdst + (size_t)gp0 * 128 + w * 16;
        float* p1 = vdst + (size_t)gp1 * 128 + w * 16;
#pragma unroll
        for (int j = 0; j < 4; ++j) {
            float4 a; a.x = vlo[4*j]; a.y = vlo[4*j+1]; a.z = vlo[4*j+2]; a.w = vlo[4*j+3];
            float4 c; c.x = vhi[4*j]; c.y = vhi[4*j+1]; c.z = vhi[4*j+2]; c.w = vhi[4*j+3];
            ((float4*)p0)[j] = a;
            ((float4*)p1)[j] = c;
        }
    }
}

extern "C" void kernel_launch(void* const* d_in, const int* in_sizes, int n_in,
                              void* d_out, int out_size, void* d_ws, size_t ws_size,
                              hipStream_t stream) {
    const float* x   = (const float*)d_in[0];
    const float* qkw = (const float*)d_in[1];
    float* out = (float*)d_out;
    unsigned short* PT = (unsigned short*)d_ws;   // 13*16384 bf16 = 416 KB

    (void)hipFuncSetAttribute((const void*)prep_kernel,
                              hipFuncAttributeMaxDynamicSharedMemorySize, PREP_LDS);
    (void)hipFuncSetAttribute((const void*)butterfly_kernel<7>,
                              hipFuncAttributeMaxDynamicSharedMemorySize, LDS_MAIN);
    (void)hipFuncSetAttribute((const void*)butterfly_kernel<6>,
                              hipFuncAttributeMaxDynamicSharedMemorySize, LDS_MAIN);

    prep_kernel<<<13, 512, PREP_LDS, stream>>>(qkw, PT);

    // stages 0..6: contiguous 128-position blocks; v init = x
    butterfly_kernel<7><<<1024, 512, LDS_MAIN, stream>>>(
        x, x, out, PT, /*s0=*/0, /*base_mul=*/128, /*h_off=*/64, /*rstride=*/1);

    // stages 7..12: 2 lo x 64 hi (stride 128); in-place on d_out
    butterfly_kernel<6><<<1024, 512, LDS_MAIN, stream>>>(
        x, out, out, PT, /*s0=*/7, /*base_mul=*/2, /*h_off=*/1, /*rstride=*/128);
}